// Round 1
// baseline (226.831 us; speedup 1.0000x reference)
//
#include <hip/hip_runtime.h>
#include <math.h>

#define SS 2048
#define DD 256
#define NB 4
#define NR (NB * SS)  // 8192 rows total

// ---------- block-wide sum over 256 threads (4 waves of 64) ----------
__device__ __forceinline__ float block_sum(float v, float* sh) {
    int lane = threadIdx.x & 63;
    int wave = threadIdx.x >> 6;
#pragma unroll
    for (int off = 32; off > 0; off >>= 1) v += __shfl_down(v, off, 64);
    if (lane == 0) sh[wave] = v;
    __syncthreads();
    float r = sh[0] + sh[1] + sh[2] + sh[3];
    __syncthreads();  // allow reuse of sh
    return r;
}

// ---------- K0: A = Wq^T @ Wk (256x256), u = Wk^T @ bq ----------
__global__ __launch_bounds__(256) void prep_kernel(
    const float* __restrict__ Wq, const float* __restrict__ Wk,
    const float* __restrict__ bq, float* __restrict__ A, float* __restrict__ u) {
    int t = threadIdx.x;
    int d = blockIdx.x;
    if (d < DD) {
        float acc = 0.0f;
        for (int i = 0; i < DD; i++) acc += Wq[i * DD + d] * Wk[i * DD + t];
        A[d * DD + t] = acc;
    } else {
        float acc = 0.0f;
        for (int i = 0; i < DD; i++) acc += Wk[i * DD + t] * bq[i];
        u[t] = acc;
    }
}

// ---------- K1: LayerNorm (torch-style: unbiased std, eps added to std) ----------
__global__ __launch_bounds__(256) void ln_kernel(
    const float* __restrict__ ctx, const float* __restrict__ ln_a,
    const float* __restrict__ ln_b, float* __restrict__ xn) {
    __shared__ float sh[4];
    int r = blockIdx.x, t = threadIdx.x;
    float v = ctx[r * DD + t];
    float mean = block_sum(v, sh) * (1.0f / 256.0f);
    float d = v - mean;
    float s2 = block_sum(d * d, sh) * (1.0f / 255.0f);  // ddof=1
    float inv = 1.0f / (sqrtf(s2) + 1e-6f);
    xn[r * DD + t] = ln_a[t] * d * inv + ln_b[t];
}

// ---------- K2: Y = Xn @ A + u   (8192 x 256) @ (256 x 256) fp32 ----------
#define BM 64
#define BN 64
#define BK 16
__global__ __launch_bounds__(256) void gemm_kernel(
    const float* __restrict__ X, const float* __restrict__ A,
    const float* __restrict__ u, float* __restrict__ Y) {
    __shared__ float Xs[BK][BM + 1];
    __shared__ float As[BK][BN];
    int tid = threadIdx.x;
    int row0 = blockIdx.x * BM;
    int col0 = blockIdx.y * BN;
    int tx = tid & 15, ty = tid >> 4;
    float acc[4][4] = {};
    for (int k0 = 0; k0 < DD; k0 += BK) {
        {   // stage X tile (BM x BK), 4 consecutive k per thread
            int m = tid >> 2;
            int kq = (tid & 3) * 4;
            float4 x4 = *(const float4*)(X + (size_t)(row0 + m) * DD + k0 + kq);
            Xs[kq + 0][m] = x4.x; Xs[kq + 1][m] = x4.y;
            Xs[kq + 2][m] = x4.z; Xs[kq + 3][m] = x4.w;
        }
        {   // stage A tile (BK x BN)
            int k = tid >> 4;
            int nq = (tid & 15) * 4;
            float4 a4 = *(const float4*)(A + (size_t)(k0 + k) * DD + col0 + nq);
            *(float4*)&As[k][nq] = a4;
        }
        __syncthreads();
#pragma unroll
        for (int k = 0; k < BK; k++) {
            float a[4], b[4];
#pragma unroll
            for (int i = 0; i < 4; i++) a[i] = Xs[k][ty * 4 + i];
#pragma unroll
            for (int j = 0; j < 4; j++) b[j] = As[k][tx * 4 + j];
#pragma unroll
            for (int i = 0; i < 4; i++)
#pragma unroll
                for (int j = 0; j < 4; j++) acc[i][j] += a[i] * b[j];
        }
        __syncthreads();
    }
    float4 uv = *(const float4*)(u + col0 + tx * 4);
#pragma unroll
    for (int i = 0; i < 4; i++) {
        float4 o = make_float4(acc[i][0] + uv.x, acc[i][1] + uv.y,
                               acc[i][2] + uv.z, acc[i][3] + uv.w);
        *(float4*)(Y + (size_t)(row0 + ty * 4 + i) * DD + col0 + tx * 4) = o;
    }
}

// ---------- K3: per-row neighbor scores -> softmax probs ----------
// pvals[r] = {p_next, p_prev, p_diag, 0}
__global__ __launch_bounds__(256) void score_kernel(
    const float* __restrict__ Y, const float* __restrict__ xn,
    const int* __restrict__ eos, float4* __restrict__ pvals) {
    __shared__ float sh[4];
    int r = blockIdx.x, t = threadIdx.x;
    int s = r & (SS - 1), b = r >> 11;
    float yv = Y[(size_t)r * DD + t];
    bool has_n = (s < SS - 1), has_p = (s > 0);
    float xnext = has_n ? xn[(size_t)(r + 1) * DD + t] : 0.0f;
    float xprev = has_p ? xn[(size_t)(r - 1) * DD + t] : 0.0f;
    float dn = block_sum(yv * xnext, sh);
    float dp = block_sum(yv * xprev, sh);
    if (t == 0) {
        size_t base = (size_t)b * SS * SS + (size_t)s * SS;
        bool mn = has_n && ((eos[base + s + 1] & 1) != 0);
        bool mp = has_p && ((eos[base + s - 1] & 1) != 0);
        float pn, pp, pd;
        if (mn && mp) {
            float d = (dn - dp) * (1.0f / 256.0f);  // scores are dot/256
            pn = 1.0f / (1.0f + expf(-d));
            pp = 1.0f / (1.0f + expf(d));
            pd = 0.0f;
        } else if (mn) { pn = 1.0f; pp = 0.0f; pd = 0.0f; }
        else if (mp)   { pn = 0.0f; pp = 1.0f; pd = 0.0f; }
        else           { pn = pp = pd = (1.0f / 2048.0f); }  // all -1e9 -> uniform
        pvals[r] = make_float4(pn, pp, pd, 0.0f);
    }
}

// ---------- K4: per-batch prefix sums of l_q (double accumulation) ----------
// l_q = log(prior[q,q+1] + (1-prior[q,q+1])*sqrt(p_next[q]*p_prev[q+1]+1e-9) + 1e-9)
// P[j] = sum_{q<j} l_q ; one block per batch, 256 threads x 8 elems
__global__ __launch_bounds__(256) void scan_kernel(
    const float4* __restrict__ pvals, const float* __restrict__ prior,
    float* __restrict__ P) {
    int b = blockIdx.x, t = threadIdx.x;
    int base_s = t * 8;
    double loc[8];
    double run = 0.0;
#pragma unroll
    for (int i = 0; i < 8; i++) {
        loc[i] = run;
        int s = base_s + i;
        float lv = 0.0f;
        if (s < SS - 1) {
            int r = b * SS + s;
            float4 pv = pvals[r];
            float4 pv1 = pvals[r + 1];
            float ns = sqrtf(pv.x * pv1.y + 1e-9f);
            float pr = prior[(size_t)b * SS * SS + (size_t)s * SS + s + 1];
            float neib = pr + (1.0f - pr) * ns;
            lv = logf(neib + 1e-9f);
        }
        run += (double)lv;
    }
    int lane = t & 63, wave = t >> 6;
    double v = run;
#pragma unroll
    for (int off = 1; off < 64; off <<= 1) {
        double uu = __shfl_up(v, off, 64);
        if (lane >= off) v += uu;
    }
    __shared__ double wsum[4];
    if (lane == 63) wsum[wave] = v;
    __syncthreads();
    double woff = 0.0;
    for (int w = 0; w < wave; w++) woff += wsum[w];
    double texcl = woff + (v - run);  // exclusive prefix of thread totals
#pragma unroll
    for (int i = 0; i < 8; i++)
        P[b * SS + base_s + i] = (float)(texcl + loc[i]);
}

// ---------- K5: fill output G[b,i,j] ----------
// i!=j: exp(P[max]-P[min]) + 1e-9 ; i==j: prior[i,i]+(1-prior)*sqrt(pd^2+1e-9)
__global__ __launch_bounds__(256) void fill_kernel(
    const float* __restrict__ P, const float4* __restrict__ pvals,
    const float* __restrict__ prior, float* __restrict__ out) {
    int blk = blockIdx.x;  // r = b*S + i
    int i = blk & (SS - 1), b = blk >> 11;
    int t = threadIdx.x;
    __shared__ float shPi, shDv;
    if (t == 0) {
        shPi = P[blk];
        float pd = pvals[blk].z;
        float prd = prior[(size_t)b * SS * SS + (size_t)i * SS + i];
        shDv = prd + (1.0f - prd) * sqrtf(pd * pd + 1e-9f);
    }
    __syncthreads();
    float Pi = shPi, dv = shDv;
    const float* Pb = P + b * SS;
    size_t outbase = (size_t)blk * SS;
    float4 pj0 = *(const float4*)(Pb + t * 8);
    float4 pj1 = *(const float4*)(Pb + t * 8 + 4);
    float pj[8] = {pj0.x, pj0.y, pj0.z, pj0.w, pj1.x, pj1.y, pj1.z, pj1.w};
    float res[8];
#pragma unroll
    for (int k = 0; k < 8; k++) {
        int j = t * 8 + k;
        float d = (j > i) ? (pj[k] - Pi) : (Pi - pj[k]);
        float val = expf(d) + 1e-9f;
        res[k] = (j == i) ? dv : val;
    }
    *(float4*)(out + outbase + t * 8) = make_float4(res[0], res[1], res[2], res[3]);
    *(float4*)(out + outbase + t * 8 + 4) = make_float4(res[4], res[5], res[6], res[7]);
}

extern "C" void kernel_launch(void* const* d_in, const int* in_sizes, int n_in,
                              void* d_out, int out_size, void* d_ws, size_t ws_size,
                              hipStream_t stream) {
    const float* context = (const float*)d_in[0];
    const float* prior   = (const float*)d_in[1];
    const float* Wq      = (const float*)d_in[2];
    const float* bq      = (const float*)d_in[3];
    const float* Wk      = (const float*)d_in[4];
    // const float* bk   = (const float*)d_in[5];  // cancels in score difference
    const float* ln_a    = (const float*)d_in[6];
    const float* ln_b    = (const float*)d_in[7];
    const int*   eos     = (const int*)d_in[8];
    float* out = (float*)d_out;

    float* ws = (float*)d_ws;
    float* xn    = ws;                       // 8192*256 = 2097152
    float* Y     = ws + 2097152;             // 2097152
    float* A     = ws + 4194304;             // 65536
    float* u     = ws + 4259840;             // 256
    float4* pv   = (float4*)(ws + 4260096);  // 8192 float4 = 32768 floats
    float* P     = ws + 4292864;             // 8192
    // total 4301056 floats = ~16.4 MB

    prep_kernel<<<DD + 1, 256, 0, stream>>>(Wq, Wk, bq, A, u);
    ln_kernel<<<NR, 256, 0, stream>>>(context, ln_a, ln_b, xn);
    gemm_kernel<<<dim3(NR / BM, DD / BN), 256, 0, stream>>>(xn, A, u, Y);
    score_kernel<<<NR, 256, 0, stream>>>(Y, xn, eos, pv);
    scan_kernel<<<NB, 256, 0, stream>>>(pv, prior, P);
    fill_kernel<<<NR, 256, 0, stream>>>(P, pv, prior, out);
}

// Round 2
// 220.547 us; speedup vs baseline: 1.0285x; 1.0285x over previous
//
#include <hip/hip_runtime.h>
#include <math.h>

#define SS 2048
#define DD 256
#define NB 4
#define NR (NB * SS)  // 8192 rows total

// ---------- K0: A = Wq^T @ Wk (256x256), u = Wk^T @ bq ----------
__global__ __launch_bounds__(256) void prep_kernel(
    const float* __restrict__ Wq, const float* __restrict__ Wk,
    const float* __restrict__ bq, float* __restrict__ A, float* __restrict__ u) {
    int t = threadIdx.x;
    int d = blockIdx.x;
    if (d < DD) {
        float acc = 0.0f;
        for (int i = 0; i < DD; i++) acc += Wq[i * DD + d] * Wk[i * DD + t];
        A[d * DD + t] = acc;
    } else {
        float acc = 0.0f;
        for (int i = 0; i < DD; i++) acc += Wk[i * DD + t] * bq[i];
        u[t] = acc;
    }
}

// ---------- K1: LayerNorm, one wave per row, float4 ----------
__global__ __launch_bounds__(256) void ln_kernel(
    const float4* __restrict__ ctx4, const float4* __restrict__ ln_a4,
    const float4* __restrict__ ln_b4, float4* __restrict__ xn4) {
    int lane = threadIdx.x & 63;
    int wave = threadIdx.x >> 6;
    int r = blockIdx.x * 4 + wave;
    float4 v = ctx4[(size_t)r * 64 + lane];
    float s = v.x + v.y + v.z + v.w;
#pragma unroll
    for (int off = 32; off > 0; off >>= 1) s += __shfl_xor(s, off, 64);
    float mean = s * (1.0f / 256.0f);
    float4 d = make_float4(v.x - mean, v.y - mean, v.z - mean, v.w - mean);
    float s2 = d.x * d.x + d.y * d.y + d.z * d.z + d.w * d.w;
#pragma unroll
    for (int off = 32; off > 0; off >>= 1) s2 += __shfl_xor(s2, off, 64);
    float inv = 1.0f / (sqrtf(s2 * (1.0f / 255.0f)) + 1e-6f);  // ddof=1, eps on std
    float4 ga = ln_a4[lane], gb = ln_b4[lane];
    xn4[(size_t)r * 64 + lane] = make_float4(
        ga.x * d.x * inv + gb.x, ga.y * d.y * inv + gb.y,
        ga.z * d.z * inv + gb.z, ga.w * d.w * inv + gb.w);
}

// ---------- K2: fused  Y = Xn@A + u  and neighbor-score softmax ----------
// Each block: 32 rows x full 256 cols in registers; then d = y.(xn_next - xn_prev)
// pvals[r] = {p_next, p_prev, p_diag, 0}
#define BK 32
#define FMA4(accv, a, bv) \
    accv.x += (a) * bv.x; accv.y += (a) * bv.y; \
    accv.z += (a) * bv.z; accv.w += (a) * bv.w;

__global__ __launch_bounds__(256) void gemm_score_kernel(
    const float* __restrict__ X, const float* __restrict__ A,
    const float* __restrict__ u, const int* __restrict__ eos,
    float4* __restrict__ pvals) {
    __shared__ float Xs[BK][33];       // 32 rows-tile transposed, padded
    __shared__ float As[BK][256];      // 32 KB
    int tid = threadIdx.x;
    int tx = tid & 15, ty = tid >> 4;  // cols: 64q + tx*4 + j ; rows: ty*2 + i
    int row0 = blockIdx.x * 32;
    const float4* X4 = (const float4*)X;
    const float4* A4 = (const float4*)A;

    float4 acc[2][4] = {};
    for (int k0 = 0; k0 < DD; k0 += BK) {
        {   // stage X tile: rows row0..+31, k k0..+31
            int m = tid >> 3;
            int kq = (tid & 7) * 4;
            float4 x4 = X4[(size_t)(row0 + m) * 64 + (k0 >> 2) + (tid & 7)];
            Xs[kq + 0][m] = x4.x; Xs[kq + 1][m] = x4.y;
            Xs[kq + 2][m] = x4.z; Xs[kq + 3][m] = x4.w;
        }
#pragma unroll
        for (int q = 0; q < 8; q++) {  // stage A tile: 32x256
            int f4 = q * 256 + tid;    // float4 index in tile
            int k = f4 >> 6, c4 = f4 & 63;
            *(float4*)&As[k][c4 * 4] = A4[(size_t)(k0 + k) * 64 + c4];
        }
        __syncthreads();
#pragma unroll
        for (int k = 0; k < BK; k++) {
            float a0 = Xs[k][ty * 2];
            float a1 = Xs[k][ty * 2 + 1];
            float4 b0 = *(const float4*)&As[k][tx * 4];
            float4 b1 = *(const float4*)&As[k][tx * 4 + 64];
            float4 b2 = *(const float4*)&As[k][tx * 4 + 128];
            float4 b3 = *(const float4*)&As[k][tx * 4 + 192];
            FMA4(acc[0][0], a0, b0) FMA4(acc[0][1], a0, b1)
            FMA4(acc[0][2], a0, b2) FMA4(acc[0][3], a0, b3)
            FMA4(acc[1][0], a1, b0) FMA4(acc[1][1], a1, b1)
            FMA4(acc[1][2], a1, b2) FMA4(acc[1][3], a1, b3)
        }
        __syncthreads();
    }
    // add u (bias term u = Wk^T bq does NOT cancel in dn - dp)
    const float4* u4 = (const float4*)u;
#pragma unroll
    for (int q = 0; q < 4; q++) {
        float4 uv = u4[q * 16 + tx];
        acc[0][q].x += uv.x; acc[0][q].y += uv.y; acc[0][q].z += uv.z; acc[0][q].w += uv.w;
        acc[1][q].x += uv.x; acc[1][q].y += uv.y; acc[1][q].z += uv.z; acc[1][q].w += uv.w;
    }
    const float4* xn4 = (const float4*)X;
#pragma unroll
    for (int i = 0; i < 2; i++) {
        int r = row0 + ty * 2 + i;
        int s = r & (SS - 1), b = r >> 11;
        bool has_n = (s < SS - 1), has_p = (s > 0);
        float partial = 0.0f;
#pragma unroll
        for (int q = 0; q < 4; q++) {
            float4 wn = has_n ? xn4[(size_t)(r + 1) * 64 + q * 16 + tx]
                              : make_float4(0, 0, 0, 0);
            float4 wp = has_p ? xn4[(size_t)(r - 1) * 64 + q * 16 + tx]
                              : make_float4(0, 0, 0, 0);
            partial += acc[i][q].x * (wn.x - wp.x) + acc[i][q].y * (wn.y - wp.y)
                     + acc[i][q].z * (wn.z - wp.z) + acc[i][q].w * (wn.w - wp.w);
        }
#pragma unroll
        for (int off = 8; off > 0; off >>= 1) partial += __shfl_xor(partial, off, 64);
        if (tx == 0) {
            size_t base = (size_t)b * SS * SS + (size_t)s * SS;
            bool mn = has_n && (eos[base + s + 1] != 0);
            bool mp = has_p && (eos[base + s - 1] != 0);
            float pn, pp, pd;
            if (mn && mp) {
                float d = partial * (1.0f / 256.0f);  // (dn - dp)/256
                pn = 1.0f / (1.0f + __expf(-d));
                pp = 1.0f - pn;
                pd = 0.0f;
            } else if (mn) { pn = 1.0f; pp = 0.0f; pd = 0.0f; }
            else if (mp)   { pn = 0.0f; pp = 1.0f; pd = 0.0f; }
            else           { pn = pp = pd = (1.0f / 2048.0f); }  // all -1e9 -> uniform
            pvals[r] = make_float4(pn, pp, pd, 0.0f);
        }
    }
}

// ---------- K3: per-batch prefix sums of l_q (double accumulation) ----------
__global__ __launch_bounds__(256) void scan_kernel(
    const float4* __restrict__ pvals, const float* __restrict__ prior,
    float* __restrict__ P) {
    int b = blockIdx.x, t = threadIdx.x;
    int base_s = t * 8;
    double loc[8];
    double run = 0.0;
#pragma unroll
    for (int i = 0; i < 8; i++) {
        loc[i] = run;
        int s = base_s + i;
        float lv = 0.0f;
        if (s < SS - 1) {
            int r = b * SS + s;
            float4 pv = pvals[r];
            float4 pv1 = pvals[r + 1];
            float ns = sqrtf(pv.x * pv1.y + 1e-9f);
            float pr = prior[(size_t)b * SS * SS + (size_t)s * SS + s + 1];
            float neib = pr + (1.0f - pr) * ns;
            lv = logf(neib + 1e-9f);
        }
        run += (double)lv;
    }
    int lane = t & 63, wave = t >> 6;
    double v = run;
#pragma unroll
    for (int off = 1; off < 64; off <<= 1) {
        double uu = __shfl_up(v, off, 64);
        if (lane >= off) v += uu;
    }
    __shared__ double wsum[4];
    if (lane == 63) wsum[wave] = v;
    __syncthreads();
    double woff = 0.0;
    for (int w = 0; w < wave; w++) woff += wsum[w];
    double texcl = woff + (v - run);  // exclusive prefix of thread totals
#pragma unroll
    for (int i = 0; i < 8; i++)
        P[b * SS + base_s + i] = (float)(texcl + loc[i]);
}

// ---------- K4: fill output G[b,i,j] ----------
__global__ __launch_bounds__(256) void fill_kernel(
    const float* __restrict__ P, const float4* __restrict__ pvals,
    const float* __restrict__ prior, float* __restrict__ out) {
    int blk = blockIdx.x;  // r = b*S + i
    int i = blk & (SS - 1), b = blk >> 11;
    int t = threadIdx.x;
    __shared__ float shPi, shDv;
    if (t == 0) {
        shPi = P[blk];
        float pd = pvals[blk].z;
        float prd = prior[(size_t)b * SS * SS + (size_t)i * SS + i];
        shDv = prd + (1.0f - prd) * sqrtf(pd * pd + 1e-9f);
    }
    __syncthreads();
    float Pi = shPi, dv = shDv;
    const float* Pb = P + b * SS;
    size_t outbase = (size_t)blk * SS;
    float4 pj0 = *(const float4*)(Pb + t * 8);
    float4 pj1 = *(const float4*)(Pb + t * 8 + 4);
    float pj[8] = {pj0.x, pj0.y, pj0.z, pj0.w, pj1.x, pj1.y, pj1.z, pj1.w};
    float res[8];
#pragma unroll
    for (int k = 0; k < 8; k++) {
        int j = t * 8 + k;
        float d = (j > i) ? (pj[k] - Pi) : (Pi - pj[k]);
        float val = __expf(d) + 1e-9f;
        res[k] = (j == i) ? dv : val;
    }
    *(float4*)(out + outbase + t * 8) = make_float4(res[0], res[1], res[2], res[3]);
    *(float4*)(out + outbase + t * 8 + 4) = make_float4(res[4], res[5], res[6], res[7]);
}

extern "C" void kernel_launch(void* const* d_in, const int* in_sizes, int n_in,
                              void* d_out, int out_size, void* d_ws, size_t ws_size,
                              hipStream_t stream) {
    const float* context = (const float*)d_in[0];
    const float* prior   = (const float*)d_in[1];
    const float* Wq      = (const float*)d_in[2];
    const float* bq      = (const float*)d_in[3];
    const float* Wk      = (const float*)d_in[4];
    // bk (d_in[5]) cancels in the score difference
    const float* ln_a    = (const float*)d_in[6];
    const float* ln_b    = (const float*)d_in[7];
    const int*   eos     = (const int*)d_in[8];
    float* out = (float*)d_out;

    float* ws = (float*)d_ws;
    float* xn    = ws;                       // 2097152 floats
    float* A     = ws + 4194304;             // 65536
    float* u     = ws + 4259840;             // 256
    float4* pv   = (float4*)(ws + 4260096);  // 8192 float4
    float* P     = ws + 4292864;             // 8192

    prep_kernel<<<DD + 1, 256, 0, stream>>>(Wq, Wk, bq, A, u);
    ln_kernel<<<NR / 4, 256, 0, stream>>>((const float4*)context,
                                          (const float4*)ln_a,
                                          (const float4*)ln_b, (float4*)xn);
    gemm_score_kernel<<<NR / 32, 256, 0, stream>>>(xn, A, u, eos, pv);
    scan_kernel<<<NB, 256, 0, stream>>>(pv, prior, P);
    fill_kernel<<<NR, 256, 0, stream>>>(P, pv, prior, out);
}

// Round 3
// 219.842 us; speedup vs baseline: 1.0318x; 1.0032x over previous
//
#include <hip/hip_runtime.h>
#include <math.h>

#define SS 2048
#define DD 256
#define NB 4
#define NR (NB * SS)  // 8192 rows total

// ---------- K0: A = Wq^T @ Wk (256x256), u = Wk^T @ bq ----------
__global__ __launch_bounds__(256) void prep_kernel(
    const float* __restrict__ Wq, const float* __restrict__ Wk,
    const float* __restrict__ bq, float* __restrict__ A, float* __restrict__ u) {
    int t = threadIdx.x;
    int d = blockIdx.x;
    if (d < DD) {
        float acc = 0.0f;
        for (int i = 0; i < DD; i++) acc += Wq[i * DD + d] * Wk[i * DD + t];
        A[d * DD + t] = acc;
    } else {
        float acc = 0.0f;
        for (int i = 0; i < DD; i++) acc += Wk[i * DD + t] * bq[i];
        u[t] = acc;
    }
}

// ---------- K1: fused LayerNorm + Y = Xn@A + u + neighbor-score softmax ----
// Block handles rows row0..row0+31. LN computed in-block for 34 rows
// (2 halo) into LDS. Then 32x256 GEMM tile in registers, then
// d = y . (xn_next - xn_prev) from LDS halo rows.
// pvals[r] = {p_next, p_prev, p_diag, 0}
#define BK 32
#define XP 260  // padded row stride: (2*260)%32=8 spreads row-broadcast banks
#define FMA4(accv, a, bv) \
    accv.x += (a) * bv.x; accv.y += (a) * bv.y; \
    accv.z += (a) * bv.z; accv.w += (a) * bv.w;

__global__ __launch_bounds__(256) void gemm_score_kernel(
    const float4* __restrict__ ctx4, const float4* __restrict__ ln_a4,
    const float4* __restrict__ ln_b4, const float* __restrict__ A,
    const float* __restrict__ u, const int* __restrict__ eos,
    float4* __restrict__ pvals) {
    __shared__ float Xn[34][XP];   // LN'd rows row0-1 .. row0+32 (~35 KB)
    __shared__ float As[BK][256];  // 32 KB
    int tid = threadIdx.x;
    int lane = tid & 63;
    int wave = tid >> 6;
    int row0 = blockIdx.x * 32;
    const float4* A4 = (const float4*)A;

    // ---- Phase 1: LayerNorm 34 rows (one wave per row, strided) ----
    float4 ga = ln_a4[lane], gb = ln_b4[lane];
    for (int rr = wave; rr < 34; rr += 4) {
        int g = row0 - 1 + rr;
        g = (g < 0) ? 0 : (g > NR - 1 ? NR - 1 : g);  // clamp (halo masked later)
        float4 v = ctx4[(size_t)g * 64 + lane];
        float s = v.x + v.y + v.z + v.w;
#pragma unroll
        for (int off = 32; off > 0; off >>= 1) s += __shfl_xor(s, off, 64);
        float mean = s * (1.0f / 256.0f);
        float4 dd = make_float4(v.x - mean, v.y - mean, v.z - mean, v.w - mean);
        float s2 = dd.x * dd.x + dd.y * dd.y + dd.z * dd.z + dd.w * dd.w;
#pragma unroll
        for (int off = 32; off > 0; off >>= 1) s2 += __shfl_xor(s2, off, 64);
        float inv = 1.0f / (sqrtf(s2 * (1.0f / 255.0f)) + 1e-6f);  // ddof=1
        float* xr = &Xn[rr][lane * 4];
        xr[0] = ga.x * dd.x * inv + gb.x;
        xr[1] = ga.y * dd.y * inv + gb.y;
        xr[2] = ga.z * dd.z * inv + gb.z;
        xr[3] = ga.w * dd.w * inv + gb.w;
    }

    // ---- Phase 2: GEMM, acc[i][q] = Y[row0+ty*2+i][64q + tx*4 .. +3] ----
    int tx = tid & 15, ty = tid >> 4;
    float4 acc[2][4] = {};
    for (int k0 = 0; k0 < DD; k0 += BK) {
#pragma unroll
        for (int q = 0; q < 8; q++) {  // stage A tile 32x256
            int f4 = q * 256 + tid;
            int k = f4 >> 6, c4 = f4 & 63;
            *(float4*)&As[k][c4 * 4] = A4[(size_t)(k0 + k) * 64 + c4];
        }
        __syncthreads();
#pragma unroll
        for (int k = 0; k < BK; k++) {
            float a0 = Xn[1 + ty * 2][k0 + k];      // row-broadcast reads
            float a1 = Xn[2 + ty * 2][k0 + k];
            float4 b0 = *(const float4*)&As[k][tx * 4];
            float4 b1 = *(const float4*)&As[k][tx * 4 + 64];
            float4 b2 = *(const float4*)&As[k][tx * 4 + 128];
            float4 b3 = *(const float4*)&As[k][tx * 4 + 192];
            FMA4(acc[0][0], a0, b0) FMA4(acc[0][1], a0, b1)
            FMA4(acc[0][2], a0, b2) FMA4(acc[0][3], a0, b3)
            FMA4(acc[1][0], a1, b0) FMA4(acc[1][1], a1, b1)
            FMA4(acc[1][2], a1, b2) FMA4(acc[1][3], a1, b3)
        }
        __syncthreads();
    }
    // ---- Phase 3: bias, neighbor diff from LDS, reduce, softmax ----
    const float4* u4 = (const float4*)u;
#pragma unroll
    for (int q = 0; q < 4; q++) {
        float4 uv = u4[q * 16 + tx];
        acc[0][q].x += uv.x; acc[0][q].y += uv.y; acc[0][q].z += uv.z; acc[0][q].w += uv.w;
        acc[1][q].x += uv.x; acc[1][q].y += uv.y; acc[1][q].z += uv.z; acc[1][q].w += uv.w;
    }
#pragma unroll
    for (int i = 0; i < 2; i++) {
        int li = 1 + ty * 2 + i;           // local row index in Xn
        int r = row0 + ty * 2 + i;
        int s = r & (SS - 1), b = r >> 11;
        bool has_n = (s < SS - 1), has_p = (s > 0);
        float fn = has_n ? 1.0f : 0.0f, fp = has_p ? 1.0f : 0.0f;
        float partial = 0.0f;
#pragma unroll
        for (int q = 0; q < 4; q++) {
            int c = q * 64 + tx * 4;
            float wx = fn * Xn[li + 1][c + 0] - fp * Xn[li - 1][c + 0];
            float wy = fn * Xn[li + 1][c + 1] - fp * Xn[li - 1][c + 1];
            float wz = fn * Xn[li + 1][c + 2] - fp * Xn[li - 1][c + 2];
            float ww = fn * Xn[li + 1][c + 3] - fp * Xn[li - 1][c + 3];
            partial += acc[i][q].x * wx + acc[i][q].y * wy
                     + acc[i][q].z * wz + acc[i][q].w * ww;
        }
#pragma unroll
        for (int off = 8; off > 0; off >>= 1) partial += __shfl_xor(partial, off, 64);
        if (tx == 0) {
            size_t base = (size_t)b * SS * SS + (size_t)s * SS;
            bool mn = has_n && (eos[base + s + 1] != 0);
            bool mp = has_p && (eos[base + s - 1] != 0);
            float pn, pp, pd;
            if (mn && mp) {
                float d = partial * (1.0f / 256.0f);  // (s_next - s_prev)
                pn = 1.0f / (1.0f + __expf(-d));
                pp = 1.0f - pn;
                pd = 0.0f;
            } else if (mn) { pn = 1.0f; pp = 0.0f; pd = 0.0f; }
            else if (mp)   { pn = 0.0f; pp = 1.0f; pd = 0.0f; }
            else           { pn = pp = pd = (1.0f / 2048.0f); }  // all -1e9
            pvals[r] = make_float4(pn, pp, pd, 0.0f);
        }
    }
}

// ---------- K2: per-batch prefix sums of l_q (double accumulation) ----------
__global__ __launch_bounds__(256) void scan_kernel(
    const float4* __restrict__ pvals, const float* __restrict__ prior,
    float* __restrict__ P) {
    int b = blockIdx.x, t = threadIdx.x;
    int base_s = t * 8;
    double loc[8];
    double run = 0.0;
#pragma unroll
    for (int i = 0; i < 8; i++) {
        loc[i] = run;
        int s = base_s + i;
        float lv = 0.0f;
        if (s < SS - 1) {
            int r = b * SS + s;
            float4 pv = pvals[r];
            float4 pv1 = pvals[r + 1];
            float ns = sqrtf(pv.x * pv1.y + 1e-9f);
            float pr = prior[(size_t)b * SS * SS + (size_t)s * SS + s + 1];
            float neib = pr + (1.0f - pr) * ns;
            lv = logf(neib + 1e-9f);
        }
        run += (double)lv;
    }
    int lane = t & 63, wave = t >> 6;
    double v = run;
#pragma unroll
    for (int off = 1; off < 64; off <<= 1) {
        double uu = __shfl_up(v, off, 64);
        if (lane >= off) v += uu;
    }
    __shared__ double wsum[4];
    if (lane == 63) wsum[wave] = v;
    __syncthreads();
    double woff = 0.0;
    for (int w = 0; w < wave; w++) woff += wsum[w];
    double texcl = woff + (v - run);  // exclusive prefix of thread totals
#pragma unroll
    for (int i = 0; i < 8; i++)
        P[b * SS + base_s + i] = (float)(texcl + loc[i]);
}

// ---------- K3: fill output G[b,i,j] ----------
__global__ __launch_bounds__(256) void fill_kernel(
    const float* __restrict__ P, const float4* __restrict__ pvals,
    const float* __restrict__ prior, float* __restrict__ out) {
    int blk = blockIdx.x;  // r = b*S + i
    int i = blk & (SS - 1), b = blk >> 11;
    int t = threadIdx.x;
    __shared__ float shPi, shDv;
    if (t == 0) {
        shPi = P[blk];
        float pd = pvals[blk].z;
        float prd = prior[(size_t)b * SS * SS + (size_t)i * SS + i];
        shDv = prd + (1.0f - prd) * sqrtf(pd * pd + 1e-9f);
    }
    __syncthreads();
    float Pi = shPi, dv = shDv;
    const float* Pb = P + b * SS;
    size_t outbase = (size_t)blk * SS;
    float4 pj0 = *(const float4*)(Pb + t * 8);
    float4 pj1 = *(const float4*)(Pb + t * 8 + 4);
    float pj[8] = {pj0.x, pj0.y, pj0.z, pj0.w, pj1.x, pj1.y, pj1.z, pj1.w};
    float res[8];
#pragma unroll
    for (int k = 0; k < 8; k++) {
        int j = t * 8 + k;
        float d = (j > i) ? (pj[k] - Pi) : (Pi - pj[k]);
        float val = __expf(d) + 1e-9f;
        res[k] = (j == i) ? dv : val;
    }
    *(float4*)(out + outbase + t * 8) = make_float4(res[0], res[1], res[2], res[3]);
    *(float4*)(out + outbase + t * 8 + 4) = make_float4(res[4], res[5], res[6], res[7]);
}

extern "C" void kernel_launch(void* const* d_in, const int* in_sizes, int n_in,
                              void* d_out, int out_size, void* d_ws, size_t ws_size,
                              hipStream_t stream) {
    const float* context = (const float*)d_in[0];
    const float* prior   = (const float*)d_in[1];
    const float* Wq      = (const float*)d_in[2];
    const float* bq      = (const float*)d_in[3];
    const float* Wk      = (const float*)d_in[4];
    // bk (d_in[5]) cancels in the score difference
    const float* ln_a    = (const float*)d_in[6];
    const float* ln_b    = (const float*)d_in[7];
    const int*   eos     = (const int*)d_in[8];
    float* out = (float*)d_out;

    float* ws = (float*)d_ws;
    float* A     = ws;                       // 65536 floats
    float* u     = ws + 65536;               // 256
    float4* pv   = (float4*)(ws + 65792);    // 8192 float4 = 32768 floats
    float* P     = ws + 98560;               // 8192

    prep_kernel<<<DD + 1, 256, 0, stream>>>(Wq, Wk, bq, A, u);
    gemm_score_kernel<<<NR / 32, 256, 0, stream>>>(
        (const float4*)context, (const float4*)ln_a, (const float4*)ln_b,
        A, u, eos, pv);
    scan_kernel<<<NB, 256, 0, stream>>>(pv, prior, P);
    fill_kernel<<<NR, 256, 0, stream>>>(P, pv, prior, out);
}